// Round 8
// baseline (158.138 us; speedup 1.0000x reference)
//
#include <hip/hip_runtime.h>

// SSIM loss v8: row-streaming, 55-named-scalar state, STATIC 11-PHASE
// ROTATION (no shift movs: phase U retires slot U; the slot receiving the
// wg(0) top-tap is overwritten via pk_mul SET, so no zeroing either).
// Retire is runtime-guarded by uniform yy in [0,32) -> one 11-phase body
// run 4x = 44 steps covers prologue+32 outputs+tail. CH_H=32, 16 chunks ->
// 6144 waves = 1536 blocks; __launch_bounds__(256,5) -> 20 waves/CU (was 12).

#define BATCH  16
#define CHAN   3
#define H_     512
#define W_     512
#define HW     (H_ * W_)
#define CH_H   32
#define NPIX   ((long)BATCH*CHAN*H_*W_)

// Normalized 11-tap Gaussian, sigma=1.5 (absmax 0 in v1/v2/v6/v7).
#define GW0 0.0010284f
#define GW1 0.0075988f
#define GW2 0.0360008f
#define GW3 0.1093554f
#define GW4 0.2130056f
#define GW5 0.2660117f

typedef float v2 __attribute__((ext_vector_type(2)));

__device__ __forceinline__ float wg(int k) {  // k literal -> folds to constant
    return (k == 0 || k == 10) ? GW0
         : (k == 1 || k == 9)  ? GW1
         : (k == 2 || k == 8)  ? GW2
         : (k == 3 || k == 7)  ? GW3
         : (k == 4 || k == 6)  ? GW4 : GW5;
}

__device__ __forceinline__ v2 pfma(v2 a, v2 b, v2 c) {
#if __has_builtin(__builtin_elementwise_fma)
    return __builtin_elementwise_fma(a, b, c);
#else
    v2 r; r.x = fmaf(a.x, b.x, c.x); r.y = fmaf(a.y, b.y, c.y); return r;
#endif
}
__device__ __forceinline__ v2 psfma(float s, v2 b, v2 c) {  // (s,s)*b + c
    v2 sv; sv.x = s; sv.y = s;
    return pfma(sv, b, c);
}

__device__ __forceinline__ float ssim_retire(float mu1, float mu2,
                                             float x11, float x22, float x12) {
    const float c1 = 1.0e-4f;
    const float c2 = 9.0e-4f;
    float mu1s = mu1 * mu1;
    float mu2s = mu2 * mu2;
    float m12  = mu1 * mu2;
    float num  = (2.0f * m12 + c1) * (2.0f * (x12 - m12) + c2);
    float den  = (mu1s + mu2s + c1) * ((x11 - mu1s) + (x22 - mu2s) + c2);
    float l = 1.0f - num * __builtin_amdgcn_rcpf(den);   // <=1ulp, thr 9.2e-3
    return fminf(fmaxf(l, 0.0f), 1.0f);
}

// Slot state: P=(mu1,mu2), Q=(x11,x22) packed, E=x12 scalar.
#define DECL(i) v2 P##i = {0.f, 0.f}, Q##i = {0.f, 0.f}; float E##i = 0.f

#define ACCW(s, wi)                          \
    P##s = psfma(wg(wi), hmm, P##s);         \
    Q##s = psfma(wg(wi), hss, Q##s);         \
    E##s = fmaf(wg(wi), hm12, E##s);

// Fresh slot: overwrite with the wg(0) top-tap contribution (no zeroing).
#define ACCSET(s)                            \
    P##s.x = GW0 * hmm.x; P##s.y = GW0 * hmm.y;  \
    Q##s.x = GW0 * hss.x; Q##s.y = GW0 * hss.y;  \
    E##s = GW0 * hm12;

#define PH_ACC(s0,s1,s2,s3,s4,s5,s6,s7,s8,s9,s10)                       \
    ACCW(s0,10) ACCW(s1,9) ACCW(s2,8) ACCW(s3,7) ACCW(s4,6) ACCW(s5,5)  \
    ACCW(s6,4)  ACCW(s7,3) ACCW(s8,2) ACCW(s9,1) ACCSET(s10)

// One pipeline step at phase = slot s0: stage cur row, prefetch next,
// h-conv, accumulate into 11 slots, retire slot s0 when yy in range.
#define STEP(s0,s1,s2,s3,s4,s5,s6,s7,s8,s9,s10) do {                    \
    st[lane] = cur;                                                     \
    if (lane < 11) st[64 + lane] = curb;                                \
    __asm__ __volatile__("" ::: "memory");                              \
    rr += 1;                                                            \
    {                                                                   \
        bool rok = (unsigned)rr < (unsigned)H_;                         \
        size_t off = (size_t)(rok ? rr : 0) * W_;                       \
        float x1 = p1[off], x2 = p2[off];                               \
        float xb1 = 0.f, xb2 = 0.f;                                     \
        if (lane < 11) { xb1 = p1b[off]; xb2 = p2b[off]; }              \
        nxt.x  = (rok && colOk)  ? x1  : 0.f;                           \
        nxt.y  = (rok && colOk)  ? x2  : 0.f;                           \
        nxtb.x = (rok && colOk2) ? xb1 : 0.f;                           \
        nxtb.y = (rok && colOk2) ? xb2 : 0.f;                           \
    }                                                                   \
    v2 hmm = {0.f, 0.f}, hss = {0.f, 0.f};                              \
    float hm12 = 0.f;                                                   \
    _Pragma("unroll")                                                   \
    for (int k = 0; k < 11; ++k) {                                      \
        v2 ab = st[lane + k];                                           \
        float wk = wg(k);                                               \
        v2 t = ab; t.x *= wk; t.y *= wk;                                \
        hmm += t;                                                       \
        hss = pfma(t, ab, hss);                                         \
        hm12 = fmaf(t.x, ab.y, hm12);                                   \
    }                                                                   \
    __asm__ __volatile__("" ::: "memory");                              \
    PH_ACC(s0,s1,s2,s3,s4,s5,s6,s7,s8,s9,s10)                           \
    if ((unsigned)yy < (unsigned)CH_H)                                  \
        lsum += ssim_retire(P##s0.x, P##s0.y, Q##s0.x, Q##s0.y, E##s0); \
    ++yy;                                                               \
    cur = nxt; curb = nxtb;                                             \
} while (0)

#define RSTEP(R) STEP(R)   // indirection so ROTn expands to 11 args
#define ROT0  0,1,2,3,4,5,6,7,8,9,10
#define ROT1  1,2,3,4,5,6,7,8,9,10,0
#define ROT2  2,3,4,5,6,7,8,9,10,0,1
#define ROT3  3,4,5,6,7,8,9,10,0,1,2
#define ROT4  4,5,6,7,8,9,10,0,1,2,3
#define ROT5  5,6,7,8,9,10,0,1,2,3,4
#define ROT6  6,7,8,9,10,0,1,2,3,4,5
#define ROT7  7,8,9,10,0,1,2,3,4,5,6
#define ROT8  8,9,10,0,1,2,3,4,5,6,7
#define ROT9  9,10,0,1,2,3,4,5,6,7,8
#define ROT10 10,0,1,2,3,4,5,6,7,8,9

__global__ __launch_bounds__(256, 5) void ssim_kernel(const float* __restrict__ img1,
                                                      const float* __restrict__ img2,
                                                      float* __restrict__ out) {
    __shared__ __align__(16) v2 sp[4][80];   // interleaved (img1,img2), 75 used
    __shared__ float wsum[4];

    const int tid  = threadIdx.x;
    const int lane = tid & 63;
    const int wv   = tid >> 6;

    const int wid   = blockIdx.x * 4 + wv;   // 0..6143
    const int plane = wid >> 7;              // / (8 strips * 16 chunks)
    const int rem   = wid & 127;
    const int strip = rem & 7;
    const int chunk = rem >> 3;              // 0..15
    const int y0 = chunk * CH_H;
    const int c0 = strip * 64;

    // sp[i] <-> cols c0-5+i of (img1, img2), i = 0..74.
    const int  colg  = c0 - 5 + lane;        // only <0 can be OOB (max 507)
    const bool colOk = (colg >= 0);
    const int  colC  = colOk ? colg : 0;
    const int  colg2  = c0 + 59 + lane;      // halo cols, lanes 0..10
    const bool colOk2 = (lane < 11) && (colg2 < W_);
    const int  col2C  = colOk2 ? colg2 : 0;

    const size_t pb = (size_t)plane * HW;
    const float* __restrict__ p1  = img1 + pb + colC;
    const float* __restrict__ p2  = img2 + pb + colC;
    const float* __restrict__ p1b = img1 + pb + col2C;
    const float* __restrict__ p2b = img2 + pb + col2C;

    v2* st = sp[wv];

    DECL(0); DECL(1); DECL(2); DECL(3); DECL(4); DECL(5);
    DECL(6); DECL(7); DECL(8); DECL(9); DECL(10);
    float lsum = 0.0f;

    int rr = y0 - 5;     // row staged by the NEXT step
    int yy = -10;        // output row retired by the NEXT step
    v2 cur, curb, nxt = {0.f, 0.f}, nxtb = {0.f, 0.f};
    {
        bool rok = (unsigned)rr < (unsigned)H_;
        size_t off = (size_t)(rok ? rr : 0) * W_;
        float x1 = p1[off], x2 = p2[off];
        float xb1 = 0.f, xb2 = 0.f;
        if (lane < 11) { xb1 = p1b[off]; xb2 = p2b[off]; }
        cur.x  = (rok && colOk)  ? x1  : 0.f;
        cur.y  = (rok && colOk)  ? x2  : 0.f;
        curb.x = (rok && colOk2) ? xb1 : 0.f;
        curb.y = (rok && colOk2) ? xb2 : 0.f;
    }

    // 4 x 11 phases = 44 steps: 10 prologue + 32 retiring + 2 junk (guarded).
    for (int t = 0; t < 4; ++t) {
        RSTEP(ROT0); RSTEP(ROT1); RSTEP(ROT2); RSTEP(ROT3); RSTEP(ROT4);
        RSTEP(ROT5); RSTEP(ROT6); RSTEP(ROT7); RSTEP(ROT8); RSTEP(ROT9);
        RSTEP(ROT10);
    }

    // Reduction: wave shuffle -> LDS -> one atomic per block.
#pragma unroll
    for (int off = 32; off > 0; off >>= 1) lsum += __shfl_down(lsum, off);
    if (lane == 0) wsum[wv] = lsum;
    __syncthreads();
    if (tid == 0) {
        float bs = wsum[0] + wsum[1] + wsum[2] + wsum[3];
        atomicAdd(out, bs * (0.5f / (float)NPIX));
    }
}

extern "C" void kernel_launch(void* const* d_in, const int* in_sizes, int n_in,
                              void* d_out, int out_size, void* d_ws, size_t ws_size,
                              hipStream_t stream) {
    const float* img1 = (const float*)d_in[0];
    const float* img2 = (const float*)d_in[1];
    float* out = (float*)d_out;

    hipMemsetAsync(out, 0, sizeof(float), stream);

    // 8 strips x 16 chunks x 48 planes = 6144 waves = 1536 blocks.
    ssim_kernel<<<dim3(6144 / 4), 256, 0, stream>>>(img1, img2, out);
}